// Round 11
// baseline (187.760 us; speedup 1.0000x reference)
//
#include <hip/hip_runtime.h>
#include <hip/hip_bf16.h>
#include <cstdint>
#include <cstddef>

using bf16 = __hip_bfloat16;
using short8 = __attribute__((ext_vector_type(8))) short;
using f32x4  = __attribute__((ext_vector_type(4))) float;

constexpr int Bc = 8;
constexpr int Tc = 4097;
constexpr int Dc = 512;         // model dim
constexpr int Hc = 8;
constexpr int Mrows = Bc * Tc;  // 32776
constexpr int Mpad2 = 33024;    // padded aout rows
constexpr int NW = 64;          // windows per (b,h)

__device__ __forceinline__ float bf2f(unsigned short u) {
    union { unsigned int i; float f; } v;
    v.i = ((unsigned int)u) << 16;
    return v.f;
}

__device__ __forceinline__ unsigned short f2b(float f) {
    union { float f; unsigned int i; } u; u.f = f;
    unsigned int r = u.i + 0x7FFFu + ((u.i >> 16) & 1u);  // RNE
    return (unsigned short)(r >> 16);
}

__device__ __forceinline__ short bfs(float f) {
    union { __hip_bfloat16 b; short s; } u;
    u.b = __float2bfloat16(f);
    return u.s;
}

__device__ __forceinline__ void gload_lds16(const void* g, void* l) {
    __builtin_amdgcn_global_load_lds(
        (const __attribute__((address_space(1))) void*)g,
        (__attribute__((address_space(3))) void*)l, 16, 0, 0);
}

// ---------------------------------------------------------------------------
// Convert + transpose weight: w fp32 [K][N] -> wT bf16 [N][K].
// ---------------------------------------------------------------------------
__global__ __launch_bounds__(256)
void k_cvt_wT(const float* __restrict__ w, bf16* __restrict__ wT, int K, int N)
{
    __shared__ float t[32][33];
    int bn = blockIdx.x * 32, bk = blockIdx.y * 32;
    int tx = threadIdx.x & 31, ty = threadIdx.x >> 5;  // 32 x 8
    #pragma unroll
    for (int j = 0; j < 4; ++j)
        t[ty + j * 8][tx] = w[(size_t)(bk + ty + j * 8) * N + bn + tx];
    __syncthreads();
    #pragma unroll
    for (int j = 0; j < 4; ++j)
        wT[(size_t)(bn + ty + j * 8) * K + bk + tx] =
            __float2bfloat16(t[tx][ty + j * 8]);
}

// ---------------------------------------------------------------------------
// QKV GEMM with FUSED x fp32->bf16 conversion in A-staging (reg-staged A).
// Same 128x128/BK=64/4-wave dbuf sync skeleton as r6 (measured optimum,
// 0 bank conflicts). A: 8 global_load_dwordx4 (fp32) issued one iteration
// ahead -> cvt once -> 4 ds_write_b128 into the SAME rotated bf16 layout.
// B: global_load_lds (unchanged). vmcnt ledger: per iter issue {A:8, B:4};
// areg deps auto-waited by compiler (~vmcnt(4), 1 iter old); explicit
// vmcnt(12) = B(t+1) landed; vmcnt(0) at t==6.
// ---------------------------------------------------------------------------
template <int NT>
__global__ __launch_bounds__(256)
void k_gemm_fA(const float* __restrict__ X, const bf16* __restrict__ Bt,
               bf16* __restrict__ C, int Mlim)
{
    constexpr int N = NT * 128;
    __shared__ short lds[32768];   // 2 bufs x (A 8192 | B 8192) shorts

    const int tid = threadIdx.x;
    const int lane = tid & 63, wave = tid >> 6;
    const int lo = lane & 15, g = lane >> 4;
    const int wr = wave >> 1, wc = wave & 1;

    // bijective XCD swizzle (m204), m-tile-major linear id
    const int nwg = 257 * NT;
    const int orig = blockIdx.x;
    const int qq = nwg >> 3, rr = nwg & 7;
    const int xc = orig & 7, o8 = orig >> 3;
    const int swz = (xc < rr ? xc * (qq + 1) : rr * (qq + 1) + (xc - rr) * qq) + o8;
    const int bm = (swz / NT) * 128, bn = (swz % NT) * 128;

    // ---- staging maps: chunk d = i*256+tid -> (row, c); rotated ck ----
    const float* aSrc[4]; bool aok[4]; int aDst[4];
    const bf16* bSrc[4]; int bDst[4];
    #pragma unroll
    for (int i = 0; i < 4; ++i) {
        int d = i * 256 + tid;
        int row = d >> 3, c = d & 7;
        int ck = (c - row) & 7;
        aSrc[i] = X + (size_t)(bm + row) * 512 + ck * 8;
        aok[i]  = (bm + row) < Mlim;
        aDst[i] = d * 8;
        bSrc[i] = Bt + (size_t)(bn + row) * 512 + ck * 8;
        bDst[i] = 8192 + d * 8;
    }

    float4 areg[4][2];

    auto A_ISSUE = [&](int kt) {
        #pragma unroll
        for (int i = 0; i < 4; ++i) {
            if (aok[i]) {
                areg[i][0] = *(const float4*)(aSrc[i] + kt * 64);
                areg[i][1] = *(const float4*)(aSrc[i] + kt * 64 + 4);
            } else {
                areg[i][0] = float4{0.f, 0.f, 0.f, 0.f};
                areg[i][1] = float4{0.f, 0.f, 0.f, 0.f};
            }
        }
    };
    auto A_WRITE = [&](int kt) {
        const int bb = (kt & 1) * 16384;
        #pragma unroll
        for (int i = 0; i < 4; ++i) {
            union { short s[8]; short8 v; } o;
            o.s[0] = bfs(areg[i][0].x); o.s[1] = bfs(areg[i][0].y);
            o.s[2] = bfs(areg[i][0].z); o.s[3] = bfs(areg[i][0].w);
            o.s[4] = bfs(areg[i][1].x); o.s[5] = bfs(areg[i][1].y);
            o.s[6] = bfs(areg[i][1].z); o.s[7] = bfs(areg[i][1].w);
            *(short8*)(lds + bb + aDst[i]) = o.v;
        }
    };
    auto B_STAGE = [&](int kt) {
        const int bb = (kt & 1) * 16384;
        #pragma unroll
        for (int i = 0; i < 4; ++i)
            gload_lds16(bSrc[i] + kt * 64, lds + bb + bDst[i]);
    };

    // ---- fragment read constants (row stride 64 shorts = 128 B) ----
    const int colk[2] = { (g + (lo & 7)) & 7, (g + 4 + (lo & 7)) & 7 };
    const int arow0 = wr * 64 + lo;
    const int brow0 = wc * 64 + lo;

    f32x4 acc[4][4] = {};

    // prologue
    A_ISSUE(0); B_STAGE(0);
    A_WRITE(0);                                       // waits A(0) regs (auto)
    A_ISSUE(1); B_STAGE(1);
    asm volatile("s_waitcnt vmcnt(12)" ::: "memory"); // B(0) landed
    asm volatile("s_waitcnt lgkmcnt(0)" ::: "memory");// A_WRITE(0) visible
    asm volatile("s_barrier" ::: "memory");           // buf0 ready

    for (int t = 0; t < 8; ++t) {
        const short* bufA = lds + (t & 1) * 16384;
        const short* bufB = bufA + 8192;

        #pragma unroll
        for (int ks = 0; ks < 2; ++ks) {
            const int col = colk[ks];
            short8 af[4], bfr[4];
            #pragma unroll
            for (int mi = 0; mi < 4; ++mi)
                af[mi] = *(const short8*)(bufA + (arow0 + mi * 16) * 64 + col * 8);
            #pragma unroll
            for (int ni = 0; ni < 4; ++ni)
                bfr[ni] = *(const short8*)(bufB + (brow0 + ni * 16) * 64 + col * 8);
            __builtin_amdgcn_s_setprio(1);
            #pragma unroll
            for (int mi = 0; mi < 4; ++mi)
                #pragma unroll
                for (int ni = 0; ni < 4; ++ni)
                    acc[mi][ni] = __builtin_amdgcn_mfma_f32_16x16x32_bf16(
                        bfr[ni], af[mi], acc[mi][ni], 0, 0, 0);
            __builtin_amdgcn_s_setprio(0);
        }

        if (t < 7) A_WRITE(t + 1);        // into buf[(t+1)&1]; parity-safe
        asm volatile("s_waitcnt lgkmcnt(0)" ::: "memory");
        asm volatile("s_barrier" ::: "memory");
        if (t < 6) {
            A_ISSUE(t + 2); B_STAGE(t + 2);               // into buf[t&1]
            asm volatile("s_waitcnt vmcnt(12)" ::: "memory"); // B(t+1) landed
            asm volatile("s_barrier" ::: "memory");
        } else if (t == 6) {
            asm volatile("s_waitcnt vmcnt(0)" ::: "memory");  // B(7) landed
            asm volatile("s_barrier" ::: "memory");
        }
    }

    // ---- epilogue: m = lane&15 dim, n = (lane>>4)*4 + r (vector stores) ----
    #pragma unroll
    for (int mi = 0; mi < 4; ++mi) {
        int m = bm + wr * 64 + mi * 16 + lo;
        if (m < Mlim) {
            #pragma unroll
            for (int ni = 0; ni < 4; ++ni) {
                int n = bn + wc * 64 + ni * 16 + g * 4;
                ushort4 o = { f2b(acc[mi][ni][0]), f2b(acc[mi][ni][1]),
                              f2b(acc[mi][ni][2]), f2b(acc[mi][ni][3]) };
                *(ushort4*)(C + (size_t)m * N + n) = o;
            }
        }
    }
}

// ---------------------------------------------------------------------------
// 128x128-tile, BK=64, 4-wave dbuf MFMA GEMM (r6 structure, verbatim).
// Used for the out-projection (bf16 A, fp32 out).
// ---------------------------------------------------------------------------
template <typename OutT, int NT>
__global__ __launch_bounds__(256)
void k_gemm_dbuf(const bf16* __restrict__ A, const bf16* __restrict__ Bt,
                 OutT* __restrict__ C, int Mlim)
{
    constexpr int N = NT * 128;
    __shared__ short lds[32768];

    const int tid = threadIdx.x;
    const int lane = tid & 63, wave = tid >> 6;
    const int lo = lane & 15, g = lane >> 4;
    const int wr = wave >> 1, wc = wave & 1;

    const int nwg = 257 * NT;
    const int orig = blockIdx.x;
    const int qq = nwg >> 3, rr = nwg & 7;
    const int xc = orig & 7, o8 = orig >> 3;
    const int swz = (xc < rr ? xc * (qq + 1) : rr * (qq + 1) + (xc - rr) * qq) + o8;
    const int bm = (swz / NT) * 128, bn = (swz % NT) * 128;

    const bf16* aSrc[4]; const bf16* bSrc[4];
    int dstOff[4];
    #pragma unroll
    for (int i = 0; i < 4; ++i) {
        int d = i * 256 + tid;
        int row = d >> 3, c = d & 7;
        int ck = (c - row) & 7;
        aSrc[i] = A  + (size_t)(bm + row) * 512 + ck * 8;
        bSrc[i] = Bt + (size_t)(bn + row) * 512 + ck * 8;
        dstOff[i] = d * 8;
    }

    auto STAGE = [&](int kt) {
        const int bb = (kt & 1) * 16384;
        #pragma unroll
        for (int i = 0; i < 4; ++i)
            gload_lds16(aSrc[i] + kt * 64, lds + bb + dstOff[i]);
        #pragma unroll
        for (int i = 0; i < 4; ++i)
            gload_lds16(bSrc[i] + kt * 64, lds + bb + 8192 + dstOff[i]);
    };

    const int colk[2] = { (g + (lo & 7)) & 7, (g + 4 + (lo & 7)) & 7 };
    const int arow0 = wr * 64 + lo;
    const int brow0 = wc * 64 + lo;

    f32x4 acc[4][4] = {};

    STAGE(0);
    STAGE(1);
    asm volatile("s_waitcnt vmcnt(8)" ::: "memory");
    __builtin_amdgcn_s_barrier();

    for (int t = 0; t < 8; ++t) {
        const short* bufA = lds + (t & 1) * 16384;
        const short* bufB = bufA + 8192;

        #pragma unroll
        for (int ks = 0; ks < 2; ++ks) {
            const int col = colk[ks];
            short8 af[4], bfr[4];
            #pragma unroll
            for (int mi = 0; mi < 4; ++mi)
                af[mi] = *(const short8*)(bufA + (arow0 + mi * 16) * 64 + col * 8);
            #pragma unroll
            for (int ni = 0; ni < 4; ++ni)
                bfr[ni] = *(const short8*)(bufB + (brow0 + ni * 16) * 64 + col * 8);
            __builtin_amdgcn_s_setprio(1);
            #pragma unroll
            for (int mi = 0; mi < 4; ++mi)
                #pragma unroll
                for (int ni = 0; ni < 4; ++ni)
                    acc[mi][ni] = __builtin_amdgcn_mfma_f32_16x16x32_bf16(
                        bfr[ni], af[mi], acc[mi][ni], 0, 0, 0);
            __builtin_amdgcn_s_setprio(0);
        }

        asm volatile("s_waitcnt lgkmcnt(0)" ::: "memory");
        __builtin_amdgcn_s_barrier();
        if (t < 6) {
            STAGE(t + 2);
            asm volatile("s_waitcnt vmcnt(8)" ::: "memory");
            __builtin_amdgcn_s_barrier();
        } else if (t == 6) {
            asm volatile("s_waitcnt vmcnt(0)" ::: "memory");
            __builtin_amdgcn_s_barrier();
        }
    }

    #pragma unroll
    for (int mi = 0; mi < 4; ++mi) {
        int m = bm + wr * 64 + mi * 16 + lo;
        if (m < Mlim) {
            #pragma unroll
            for (int ni = 0; ni < 4; ++ni) {
                int n = bn + wc * 64 + ni * 16 + g * 4;
                if constexpr (sizeof(OutT) == 2) {
                    ushort4 o = { f2b(acc[mi][ni][0]), f2b(acc[mi][ni][1]),
                                  f2b(acc[mi][ni][2]), f2b(acc[mi][ni][3]) };
                    *(ushort4*)((bf16*)C + (size_t)m * N + n) = o;
                } else {
                    float4 o = { acc[mi][ni][0], acc[mi][ni][1],
                                 acc[mi][ni][2], acc[mi][ni][3] };
                    *(float4*)((float*)C + (size_t)m * N + n) = o;
                }
            }
        }
    }
}

// ---------------------------------------------------------------------------
// Window attention (tokens 1..4096), MFMA, with fused token-0 partials.
// (unchanged from r9)
// ---------------------------------------------------------------------------
__global__ __launch_bounds__(256)
void k_attn_win(const bf16* __restrict__ qkv, bf16* __restrict__ aout,
                float* __restrict__ part)
{
    __shared__ __attribute__((aligned(16))) unsigned short pS[64 * 64];
    __shared__ __attribute__((aligned(16))) unsigned short vT[64 * 64];
    __shared__ float q0s[64];
    __shared__ float pTok[64];
    __shared__ float oPart[4][64];

    const int n = blockIdx.x, h = blockIdx.y, b = blockIdx.z;
    const int tid = threadIdx.x;
    const int wave = tid >> 6, lane = tid & 63;
    const int lo = lane & 15, g = lane >> 4;

    const bf16* base = qkv + ((size_t)b * Tc + 1 + (size_t)n * 64) * 1536 + h * 64;
    const bf16* kbase = base + 512;
    const bf16* vbase = base + 1024;

    {
        const int key = tid & 63;
        const int d0 = (tid >> 6) * 16;
        const bf16* vp = vbase + (size_t)key * 1536 + d0;
        ushort4 u[4];
        #pragma unroll
        for (int q = 0; q < 4; ++q) u[q] = *(const ushort4*)(vp + q * 4);
        const unsigned short vals[16] = {
            u[0].x, u[0].y, u[0].z, u[0].w, u[1].x, u[1].y, u[1].z, u[1].w,
            u[2].x, u[2].y, u[2].z, u[2].w, u[3].x, u[3].y, u[3].z, u[3].w };
        #pragma unroll
        for (int j = 0; j < 16; ++j) {
            int d = d0 + j;
            int byteoff = d * 128 + ((key * 2) ^ ((d & 7) << 4));
            *(unsigned short*)((char*)vT + byteoff) = vals[j];
        }
    }

    if (tid < 64)
        q0s[tid] = bf2f(*(const unsigned short*)
            (qkv + (size_t)b * Tc * 1536 + h * 64 + tid));

    short8 qf[2];
    {
        const bf16* qp = base + (size_t)(wave * 16 + lo) * 1536 + g * 8;
        qf[0] = *(const short8*)(qp);
        qf[1] = *(const short8*)(qp + 32);
    }

    f32x4 sacc[4] = {};
    #pragma unroll
    for (int ni = 0; ni < 4; ++ni) {
        const bf16* kp = kbase + (size_t)(ni * 16 + lo) * 1536 + g * 8;
        short8 k0 = *(const short8*)(kp);
        short8 k1 = *(const short8*)(kp + 32);
        sacc[ni] = __builtin_amdgcn_mfma_f32_16x16x32_bf16(qf[0], k0, sacc[ni], 0, 0, 0);
        sacc[ni] = __builtin_amdgcn_mfma_f32_16x16x32_bf16(qf[1], k1, sacc[ni], 0, 0, 0);
    }

    __syncthreads();  // barrier 1: vT + q0s ready

    float m_w = 0.f, s_w = 0.f;
    if (wave == 0) {
        const bf16* kp = kbase + (size_t)lane * 1536;
        float l = 0.f;
        #pragma unroll
        for (int d8 = 0; d8 < 8; ++d8) {
            short8 kv = *(const short8*)(kp + d8 * 8);
            #pragma unroll
            for (int e = 0; e < 8; ++e)
                l = fmaf(q0s[d8 * 8 + e], bf2f((unsigned short)kv[e]), l);
        }
        l *= 0.125f;
        float mm = l;
        #pragma unroll
        for (int off = 1; off < 64; off <<= 1) mm = fmaxf(mm, __shfl_xor(mm, off));
        float p = __expf(l - mm);
        float ss = p;
        #pragma unroll
        for (int off = 1; off < 64; off <<= 1) ss += __shfl_xor(ss, off);
        pTok[lane] = p;
        m_w = mm; s_w = ss;
    }

    float pv[4][4];
    float inv[4];
    #pragma unroll
    for (int r = 0; r < 4; ++r) {
        float m = fmaxf(fmaxf(sacc[0][r], sacc[1][r]),
                        fmaxf(sacc[2][r], sacc[3][r])) * 0.125f;
        m = fmaxf(m, __shfl_xor(m, 1));
        m = fmaxf(m, __shfl_xor(m, 2));
        m = fmaxf(m, __shfl_xor(m, 4));
        m = fmaxf(m, __shfl_xor(m, 8));
        float s = 0.f;
        #pragma unroll
        for (int ni = 0; ni < 4; ++ni) {
            float e = __expf(sacc[ni][r] * 0.125f - m);
            pv[ni][r] = e;
            s += e;
        }
        s += __shfl_xor(s, 1);
        s += __shfl_xor(s, 2);
        s += __shfl_xor(s, 4);
        s += __shfl_xor(s, 8);
        inv[r] = 1.f / s;
    }

    #pragma unroll
    for (int ni = 0; ni < 4; ++ni) {
        #pragma unroll
        for (int r = 0; r < 4; ++r) {
            int qrow = wave * 16 + g * 4 + r;
            int col = ni * 16 + lo;
            int byteoff = qrow * 128 + ((col * 2) ^ ((qrow & 7) << 4));
            *(unsigned short*)((char*)pS + byteoff) = f2b(pv[ni][r]);
        }
    }
    __syncthreads();  // barrier 2: pS + pTok ready

    f32x4 oacc[4] = {};
    #pragma unroll
    for (int s = 0; s < 2; ++s) {
        int arow2 = wave * 16 + lo;
        int abyte = arow2 * 128 + (((s * 32 + g * 8) * 2) ^ ((arow2 & 7) << 4));
        short8 pa = *(const short8*)((const char*)pS + abyte);
        #pragma unroll
        for (int nd = 0; nd < 4; ++nd) {
            int d = nd * 16 + lo;
            int bbyte = d * 128 + (((s * 32 + g * 8) * 2) ^ ((d & 7) << 4));
            short8 vb = *(const short8*)((const char*)vT + bbyte);
            oacc[nd] = __builtin_amdgcn_mfma_f32_16x16x32_bf16(pa, vb, oacc[nd], 0, 0, 0);
        }
    }

    {
        const int d = tid & 63, qq = tid >> 6;
        float po = 0.f;
        #pragma unroll
        for (int j16 = 0; j16 < 16; ++j16) {
            int j = qq * 16 + j16;
            int byteoff = d * 128 + ((j * 2) ^ ((d & 7) << 4));
            po = fmaf(pTok[j],
                      bf2f(*(const unsigned short*)((const char*)vT + byteoff)),
                      po);
        }
        oPart[qq][d] = po;
    }

    #pragma unroll
    for (int nd = 0; nd < 4; ++nd) {
        #pragma unroll
        for (int r = 0; r < 4; ++r) {
            int t = 1 + n * 64 + wave * 16 + g * 4 + r;
            aout[((size_t)b * Tc + t) * Dc + h * 64 + nd * 16 + lo] =
                __float2bfloat16(oacc[nd][r] * inv[r]);
        }
    }

    __syncthreads();  // barrier 3: oPart ready

    if (tid < 64) {
        float o0 = oPart[0][tid] + oPart[1][tid] + oPart[2][tid] + oPart[3][tid];
        float* pout = part + ((size_t)(b * Hc + h) * NW + n) * 66;
        pout[tid] = o0;
        if (tid == 0) { pout[64] = m_w; pout[65] = s_w; }
    }
}

// ---------------------------------------------------------------------------
// Token-0 reduce: combine 64 window partials + the key-0 term per (b,h).
// (unchanged from r9)
// ---------------------------------------------------------------------------
__global__ __launch_bounds__(64)
void k_tok0_reduce(const float* __restrict__ part, const bf16* __restrict__ qkv,
                   bf16* __restrict__ aout)
{
    const int h = blockIdx.x, b = blockIdx.y;
    const int lane = threadIdx.x;
    const float* basep = part + (size_t)(b * Hc + h) * NW * 66;
    const bf16* qrow = qkv + (size_t)b * Tc * 1536 + h * 64;

    float l0 = bf2f(*(const unsigned short*)(qrow + lane)) *
               bf2f(*(const unsigned short*)(qrow + 512 + lane));
    #pragma unroll
    for (int off = 1; off < 64; off <<= 1) l0 += __shfl_xor(l0, off);
    l0 *= 0.125f;

    float M = basep[lane * 66 + 64];
    #pragma unroll
    for (int off = 1; off < 64; off <<= 1) M = fmaxf(M, __shfl_xor(M, off));
    M = fmaxf(M, l0);

    float S = 0.f, o = 0.f;
    for (int c = 0; c < NW; ++c) {
        const float* pp = basep + c * 66;
        float w = __expf(pp[64] - M);
        S += pp[65] * w;
        o = fmaf(pp[lane], w, o);
    }
    float p0 = __expf(l0 - M);
    S += p0;
    o = fmaf(p0, bf2f(*(const unsigned short*)(qrow + 1024 + lane)), o);

    aout[(size_t)b * Tc * Dc + h * 64 + lane] = __float2bfloat16(o / S);
}

// ---------------------------------------------------------------------------
extern "C" void kernel_launch(void* const* d_in, const int* in_sizes, int n_in,
                              void* d_out, int out_size, void* d_ws, size_t ws_size,
                              hipStream_t stream)
{
    const float* x     = (const float*)d_in[0];
    const float* w_qkv = (const float*)d_in[1];
    const float* w_out = (const float*)d_in[2];
    float* out = (float*)d_out;

    // ws layout (bf16 elems): qkv [Mrows*1536] | aout [Mpad2*512] |
    // wqT [1536*512] | woT [512*512]. token-0 partials reuse wqT (dead after
    // QKV GEMM): 8*8*64*66*4 B = 1.08 MB <= 1.57 MB.
    // aout pad rows (>= Mrows) are never written: out-GEMM reads their poison
    // into tail tiles but the corresponding C rows are store-predicated.
    bf16* qkv  = (bf16*)d_ws;
    bf16* aout = qkv  + (size_t)Mrows * 1536;
    bf16* wqT  = aout + (size_t)Mpad2 * 512;
    bf16* woT  = wqT  + (size_t)1536 * 512;
    float* part = (float*)wqT;

    // 1) weight conversions (x conversion fused into QKV GEMM A-staging)
    k_cvt_wT<<<dim3(48, 16), 256, 0, stream>>>(w_qkv, wqT, 512, 1536);
    k_cvt_wT<<<dim3(16, 16), 256, 0, stream>>>(w_out, woT, 512, 512);

    // 2) qkv = x @ w_qkv  (dbuf MFMA, A reg-staged fp32->bf16)
    k_gemm_fA<12><<<257 * 12, 256, 0, stream>>>(x, wqT, qkv, Mrows);

    // 3) attention: MFMA windows with fused token-0 partials, then reduce
    k_attn_win<<<dim3(64, Hc, Bc), 256, 0, stream>>>(qkv, aout, part);
    k_tok0_reduce<<<dim3(Hc, Bc), dim3(64), 0, stream>>>(part, qkv, aout);

    // 4) out = attn_out @ w_out
    k_gemm_dbuf<float, 4><<<257 * 4, 256, 0, stream>>>(aout, woT, out, Mrows);
}

// Round 12
// 185.065 us; speedup vs baseline: 1.0146x; 1.0146x over previous
//
#include <hip/hip_runtime.h>
#include <hip/hip_bf16.h>
#include <cstdint>
#include <cstddef>

using bf16 = __hip_bfloat16;
using short8 = __attribute__((ext_vector_type(8))) short;
using f32x4  = __attribute__((ext_vector_type(4))) float;

constexpr int Bc = 8;
constexpr int Tc = 4097;
constexpr int Dc = 512;         // model dim
constexpr int Hc = 8;
constexpr int Mrows = Bc * Tc;  // 32776
constexpr int Mpad2 = 33024;    // 129*256 padded A rows
constexpr int NW = 64;          // windows per (b,h)

__device__ __forceinline__ float bf2f(unsigned short u) {
    union { unsigned int i; float f; } v;
    v.i = ((unsigned int)u) << 16;
    return v.f;
}

__device__ __forceinline__ unsigned short f2b(float f) {
    union { float f; unsigned int i; } u; u.f = f;
    unsigned int r = u.i + 0x7FFFu + ((u.i >> 16) & 1u);  // RNE
    return (unsigned short)(r >> 16);
}

__device__ __forceinline__ void gload_lds16(const void* g, void* l) {
    __builtin_amdgcn_global_load_lds(
        (const __attribute__((address_space(1))) void*)g,
        (__attribute__((address_space(3))) void*)l, 16, 0, 0);
}

// ---------------------------------------------------------------------------
// Convert x (fp32 [Mrows][512]) -> bf16 [Mpad2][512]; pad rows zeroed.
// ---------------------------------------------------------------------------
__global__ __launch_bounds__(256)
void k_cvt_x(const float* __restrict__ x, bf16* __restrict__ xb)
{
    size_t i8 = ((size_t)blockIdx.x * 256 + threadIdx.x) * 8;
    if (i8 >= (size_t)Mpad2 * 512) return;
    union { short s[8]; short8 v; } o;
    if (i8 < (size_t)Mrows * 512) {
        float4 v0 = *(const float4*)(x + i8);
        float4 v1 = *(const float4*)(x + i8 + 4);
        o.s[0] = (short)f2b(v0.x); o.s[1] = (short)f2b(v0.y);
        o.s[2] = (short)f2b(v0.z); o.s[3] = (short)f2b(v0.w);
        o.s[4] = (short)f2b(v1.x); o.s[5] = (short)f2b(v1.y);
        o.s[6] = (short)f2b(v1.z); o.s[7] = (short)f2b(v1.w);
    } else {
        o.v = short8{0,0,0,0,0,0,0,0};
    }
    *(short8*)((short*)xb + i8) = o.v;
}

// ---------------------------------------------------------------------------
// Convert + transpose weight: w fp32 [K][N] -> wT bf16 [N][K].
// ---------------------------------------------------------------------------
__global__ __launch_bounds__(256)
void k_cvt_wT(const float* __restrict__ w, bf16* __restrict__ wT, int K, int N)
{
    __shared__ float t[32][33];
    int bn = blockIdx.x * 32, bk = blockIdx.y * 32;
    int tx = threadIdx.x & 31, ty = threadIdx.x >> 5;  // 32 x 8
    #pragma unroll
    for (int j = 0; j < 4; ++j)
        t[ty + j * 8][tx] = w[(size_t)(bk + ty + j * 8) * N + bn + tx];
    __syncthreads();
    #pragma unroll
    for (int j = 0; j < 4; ++j)
        wT[(size_t)(bn + ty + j * 8) * K + bk + tx] =
            __float2bfloat16(t[tx][ty + j * 8]);
}

// ---------------------------------------------------------------------------
// 8-phase fine-interleaved MFMA GEMM (m201-template port).
// 256x256 tile, BK=64, 8 waves (2M x 4N), wave tile 128x64, 128 KiB LDS,
// double-buffered per K-tile. Per K-tile = 4 phases; phase p:
//   { ds_read A-frags quadrant p (B frags read once at p0) |
//     stage 2/8 units of tile t+1 | counted vmcnt at p1/p3 |
//     barrier | lgkmcnt(0)+sched_barrier | setprio(1) 16 MFMA setprio(0) |
//     barrier }
// Staging units (1 gload/thread each): u0..3 = B row-quarters; u4..7 = A
// quarter-sets {q*32..q*32+32} U {128+q*32..+32} (q = phase that consumes).
// vmcnt ledger (2 loads/phase, 8/iter): W@p1 = vmcnt(4) -> tile t A-q2/q3
// landed (issued (t-1).p3, 3-phase slack); W@p3 = vmcnt(2) -> tile t+1
// B+A-q0/q1 landed before next iter (2-phase slack). Never drain-0 mid-loop.
// Swizzle: r6-verified rotation, chunk pos c holds source chunk (c-row)&7.
// ---------------------------------------------------------------------------
template <int NT>
__global__ __launch_bounds__(512, 1)
void k_gemm_8p(const bf16* __restrict__ A, const bf16* __restrict__ Bt,
               bf16* __restrict__ C, int Mlim)
{
    constexpr int N = NT * 256;
    __shared__ short lds[65536];   // 2 bufs x (A 16384 | B 16384) shorts

    const int tid = threadIdx.x;
    const int lane = tid & 63, wave = tid >> 6;
    const int lo = lane & 15, g = lane >> 4;
    const int wr = wave >> 2, wc = wave & 3;

    // bijective XCD swizzle (m204), m-tile-major linear id
    const int nwg = 129 * NT;
    const int orig = blockIdx.x;
    const int qq = nwg >> 3, rr = nwg & 7;
    const int xc = orig & 7, o8 = orig >> 3;
    const int swz = (xc < rr ? xc * (qq + 1) : rr * (qq + 1) + (xc - rr) * qq) + o8;
    const int bm = (swz / NT) * 256, bn = (swz % NT) * 256;

    // ---- staging units: 8 units x 512 chunks; this thread's chunk per unit
    const bf16* srcU[8];
    int dstU[8];
    {
        const int lr = tid >> 3, c = tid & 7;
        #pragma unroll
        for (int u = 0; u < 8; ++u) {
            int row;
            const bf16* gbase;
            int dbase;
            if (u < 4) {                       // B quarter u: rows u*64..+64
                row = u * 64 + lr;
                gbase = Bt + (size_t)(bn + row) * 512;
                dbase = 16384 + row * 64;
            } else {                           // A quarter-set u-4
                int qa = u - 4;
                row = (lr < 32) ? (qa * 32 + lr) : (128 + qa * 32 + (lr - 32));
                gbase = A + (size_t)(bm + row) * 512;
                dbase = row * 64;
            }
            int ck = (c - row) & 7;            // rotated source chunk
            srcU[u] = gbase + ck * 8;
            dstU[u] = dbase + c * 8;           // linear LDS dest (shorts)
        }
    }

    // ---- fragment read constants ----
    const int colk[2] = { (g + (lo & 7)) & 7, (g + 4 + (lo & 7)) & 7 };
    const int browBase = wc * 64 + lo;         // B rows for this wave

    f32x4 acc[8][4] = {};

    // ---- prologue: tile 0, units in order ----
    #pragma unroll
    for (int u = 0; u < 8; ++u)
        gload_lds16(srcU[u], lds + dstU[u]);
    asm volatile("s_waitcnt vmcnt(2)" ::: "memory");   // units 0..5 landed
    asm volatile("s_barrier" ::: "memory");

    for (int t = 0; t < 8; ++t) {
        const short* buf = lds + (t & 1) * 32768;
        const int sb = ((t + 1) & 1) * 32768;
        short8 bfr[4][2];

        #pragma unroll
        for (int p = 0; p < 4; ++p) {
            // ds_read A-frags for quadrant p; B frags once per tile
            short8 af[2][2];
            #pragma unroll
            for (int m2 = 0; m2 < 2; ++m2)
                #pragma unroll
                for (int ks = 0; ks < 2; ++ks)
                    af[m2][ks] = *(const short8*)(
                        buf + (wr * 128 + (2 * p + m2) * 16 + lo) * 64 + colk[ks] * 8);
            if (p == 0) {
                #pragma unroll
                for (int ni = 0; ni < 4; ++ni)
                    #pragma unroll
                    for (int ks = 0; ks < 2; ++ks)
                        bfr[ni][ks] = *(const short8*)(
                            buf + 16384 + (browBase + ni * 16) * 64 + colk[ks] * 8);
            }

            // stage 2 units of tile t+1
            if (t < 7) {
                gload_lds16(srcU[2 * p]     + (t + 1) * 64, lds + sb + dstU[2 * p]);
                gload_lds16(srcU[2 * p + 1] + (t + 1) * 64, lds + sb + dstU[2 * p + 1]);
            }

            // counted waits (see ledger above)
            if (p == 1) {
                if (t < 7) asm volatile("s_waitcnt vmcnt(4)" ::: "memory");
                else       asm volatile("s_waitcnt vmcnt(0)" ::: "memory");
            }
            if (p == 3 && t < 7)
                asm volatile("s_waitcnt vmcnt(2)" ::: "memory");

            asm volatile("s_barrier" ::: "memory");
            asm volatile("s_waitcnt lgkmcnt(0)" ::: "memory");
            __builtin_amdgcn_sched_barrier(0);

            __builtin_amdgcn_s_setprio(1);
            #pragma unroll
            for (int m2 = 0; m2 < 2; ++m2)
                #pragma unroll
                for (int ni = 0; ni < 4; ++ni)
                    #pragma unroll
                    for (int ks = 0; ks < 2; ++ks)
                        acc[2 * p + m2][ni] = __builtin_amdgcn_mfma_f32_16x16x32_bf16(
                            bfr[ni][ks], af[m2][ks], acc[2 * p + m2][ni], 0, 0, 0);
            __builtin_amdgcn_s_setprio(0);
            asm volatile("s_barrier" ::: "memory");
        }
    }

    // ---- epilogue: m = lane&15 dim, n = (lane>>4)*4 + r (vector stores) ----
    #pragma unroll
    for (int mi = 0; mi < 8; ++mi) {
        int m = bm + wr * 128 + mi * 16 + lo;
        if (m < Mlim) {
            #pragma unroll
            for (int ni = 0; ni < 4; ++ni) {
                int n = bn + wc * 64 + ni * 16 + g * 4;
                ushort4 o = { f2b(acc[mi][ni][0]), f2b(acc[mi][ni][1]),
                              f2b(acc[mi][ni][2]), f2b(acc[mi][ni][3]) };
                *(ushort4*)(C + (size_t)m * N + n) = o;
            }
        }
    }
}

// ---------------------------------------------------------------------------
// 128x128-tile, BK=64, 4-wave dbuf MFMA GEMM (r6 structure, verbatim).
// Used for the out-projection (bf16 A, fp32 out) — near memory floor.
// ---------------------------------------------------------------------------
template <typename OutT, int NT>
__global__ __launch_bounds__(256)
void k_gemm_dbuf(const bf16* __restrict__ A, const bf16* __restrict__ Bt,
                 OutT* __restrict__ C, int Mlim)
{
    constexpr int N = NT * 128;
    __shared__ short lds[32768];

    const int tid = threadIdx.x;
    const int lane = tid & 63, wave = tid >> 6;
    const int lo = lane & 15, g = lane >> 4;
    const int wr = wave >> 1, wc = wave & 1;

    const int nwg = 257 * NT;
    const int orig = blockIdx.x;
    const int qq = nwg >> 3, rr = nwg & 7;
    const int xc = orig & 7, o8 = orig >> 3;
    const int swz = (xc < rr ? xc * (qq + 1) : rr * (qq + 1) + (xc - rr) * qq) + o8;
    const int bm = (swz / NT) * 128, bn = (swz % NT) * 128;

    const bf16* aSrc[4]; const bf16* bSrc[4];
    int dstOff[4];
    #pragma unroll
    for (int i = 0; i < 4; ++i) {
        int d = i * 256 + tid;
        int row = d >> 3, c = d & 7;
        int ck = (c - row) & 7;
        aSrc[i] = A  + (size_t)(bm + row) * 512 + ck * 8;
        bSrc[i] = Bt + (size_t)(bn + row) * 512 + ck * 8;
        dstOff[i] = d * 8;
    }

    auto STAGE = [&](int kt) {
        const int bb = (kt & 1) * 16384;
        #pragma unroll
        for (int i = 0; i < 4; ++i)
            gload_lds16(aSrc[i] + kt * 64, lds + bb + dstOff[i]);
        #pragma unroll
        for (int i = 0; i < 4; ++i)
            gload_lds16(bSrc[i] + kt * 64, lds + bb + 8192 + dstOff[i]);
    };

    const int colk[2] = { (g + (lo & 7)) & 7, (g + 4 + (lo & 7)) & 7 };
    const int arow0 = wr * 64 + lo;
    const int brow0 = wc * 64 + lo;

    f32x4 acc[4][4] = {};

    STAGE(0);
    STAGE(1);
    asm volatile("s_waitcnt vmcnt(8)" ::: "memory");
    __builtin_amdgcn_s_barrier();

    for (int t = 0; t < 8; ++t) {
        const short* bufA = lds + (t & 1) * 16384;
        const short* bufB = bufA + 8192;

        #pragma unroll
        for (int ks = 0; ks < 2; ++ks) {
            const int col = colk[ks];
            short8 af[4], bfr[4];
            #pragma unroll
            for (int mi = 0; mi < 4; ++mi)
                af[mi] = *(const short8*)(bufA + (arow0 + mi * 16) * 64 + col * 8);
            #pragma unroll
            for (int ni = 0; ni < 4; ++ni)
                bfr[ni] = *(const short8*)(bufB + (brow0 + ni * 16) * 64 + col * 8);
            __builtin_amdgcn_s_setprio(1);
            #pragma unroll
            for (int mi = 0; mi < 4; ++mi)
                #pragma unroll
                for (int ni = 0; ni < 4; ++ni)
                    acc[mi][ni] = __builtin_amdgcn_mfma_f32_16x16x32_bf16(
                        bfr[ni], af[mi], acc[mi][ni], 0, 0, 0);
            __builtin_amdgcn_s_setprio(0);
        }

        asm volatile("s_waitcnt lgkmcnt(0)" ::: "memory");
        __builtin_amdgcn_s_barrier();
        if (t < 6) {
            STAGE(t + 2);
            asm volatile("s_waitcnt vmcnt(8)" ::: "memory");
            __builtin_amdgcn_s_barrier();
        } else if (t == 6) {
            asm volatile("s_waitcnt vmcnt(0)" ::: "memory");
            __builtin_amdgcn_s_barrier();
        }
    }

    #pragma unroll
    for (int mi = 0; mi < 4; ++mi) {
        int m = bm + wr * 64 + mi * 16 + lo;
        if (m < Mlim) {
            #pragma unroll
            for (int ni = 0; ni < 4; ++ni) {
                int n = bn + wc * 64 + ni * 16 + g * 4;
                if constexpr (sizeof(OutT) == 2) {
                    ushort4 o = { f2b(acc[mi][ni][0]), f2b(acc[mi][ni][1]),
                                  f2b(acc[mi][ni][2]), f2b(acc[mi][ni][3]) };
                    *(ushort4*)((bf16*)C + (size_t)m * N + n) = o;
                } else {
                    float4 o = { acc[mi][ni][0], acc[mi][ni][1],
                                 acc[mi][ni][2], acc[mi][ni][3] };
                    *(float4*)((float*)C + (size_t)m * N + n) = o;
                }
            }
        }
    }
}

// ---------------------------------------------------------------------------
// Window attention (tokens 1..4096), MFMA, with fused token-0 partials.
// (r9 version, unchanged)
// ---------------------------------------------------------------------------
__global__ __launch_bounds__(256)
void k_attn_win(const bf16* __restrict__ qkv, bf16* __restrict__ aout,
                float* __restrict__ part)
{
    __shared__ __attribute__((aligned(16))) unsigned short pS[64 * 64];
    __shared__ __attribute__((aligned(16))) unsigned short vT[64 * 64];
    __shared__ float q0s[64];
    __shared__ float pTok[64];
    __shared__ float oPart[4][64];

    const int n = blockIdx.x, h = blockIdx.y, b = blockIdx.z;
    const int tid = threadIdx.x;
    const int wave = tid >> 6, lane = tid & 63;
    const int lo = lane & 15, g = lane >> 4;

    const bf16* base = qkv + ((size_t)b * Tc + 1 + (size_t)n * 64) * 1536 + h * 64;
    const bf16* kbase = base + 512;
    const bf16* vbase = base + 1024;

    {
        const int key = tid & 63;
        const int d0 = (tid >> 6) * 16;
        const bf16* vp = vbase + (size_t)key * 1536 + d0;
        ushort4 u[4];
        #pragma unroll
        for (int q = 0; q < 4; ++q) u[q] = *(const ushort4*)(vp + q * 4);
        const unsigned short vals[16] = {
            u[0].x, u[0].y, u[0].z, u[0].w, u[1].x, u[1].y, u[1].z, u[1].w,
            u[2].x, u[2].y, u[2].z, u[2].w, u[3].x, u[3].y, u[3].z, u[3].w };
        #pragma unroll
        for (int j = 0; j < 16; ++j) {
            int d = d0 + j;
            int byteoff = d * 128 + ((key * 2) ^ ((d & 7) << 4));
            *(unsigned short*)((char*)vT + byteoff) = vals[j];
        }
    }

    if (tid < 64)
        q0s[tid] = bf2f(*(const unsigned short*)
            (qkv + (size_t)b * Tc * 1536 + h * 64 + tid));

    short8 qf[2];
    {
        const bf16* qp = base + (size_t)(wave * 16 + lo) * 1536 + g * 8;
        qf[0] = *(const short8*)(qp);
        qf[1] = *(const short8*)(qp + 32);
    }

    f32x4 sacc[4] = {};
    #pragma unroll
    for (int ni = 0; ni < 4; ++ni) {
        const bf16* kp = kbase + (size_t)(ni * 16 + lo) * 1536 + g * 8;
        short8 k0 = *(const short8*)(kp);
        short8 k1 = *(const short8*)(kp + 32);
        sacc[ni] = __builtin_amdgcn_mfma_f32_16x16x32_bf16(qf[0], k0, sacc[ni], 0, 0, 0);
        sacc[ni] = __builtin_amdgcn_mfma_f32_16x16x32_bf16(qf[1], k1, sacc[ni], 0, 0, 0);
    }

    __syncthreads();  // barrier 1: vT + q0s ready

    float m_w = 0.f, s_w = 0.f;
    if (wave == 0) {
        const bf16* kp = kbase + (size_t)lane * 1536;
        float l = 0.f;
        #pragma unroll
        for (int d8 = 0; d8 < 8; ++d8) {
            short8 kv = *(const short8*)(kp + d8 * 8);
            #pragma unroll
            for (int e = 0; e < 8; ++e)
                l = fmaf(q0s[d8 * 8 + e], bf2f((unsigned short)kv[e]), l);
        }
        l *= 0.125f;
        float mm = l;
        #pragma unroll
        for (int off = 1; off < 64; off <<= 1) mm = fmaxf(mm, __shfl_xor(mm, off));
        float p = __expf(l - mm);
        float ss = p;
        #pragma unroll
        for (int off = 1; off < 64; off <<= 1) ss += __shfl_xor(ss, off);
        pTok[lane] = p;
        m_w = mm; s_w = ss;
    }

    float pv[4][4];
    float inv[4];
    #pragma unroll
    for (int r = 0; r < 4; ++r) {
        float m = fmaxf(fmaxf(sacc[0][r], sacc[1][r]),
                        fmaxf(sacc[2][r], sacc[3][r])) * 0.125f;
        m = fmaxf(m, __shfl_xor(m, 1));
        m = fmaxf(m, __shfl_xor(m, 2));
        m = fmaxf(m, __shfl_xor(m, 4));
        m = fmaxf(m, __shfl_xor(m, 8));
        float s = 0.f;
        #pragma unroll
        for (int ni = 0; ni < 4; ++ni) {
            float e = __expf(sacc[ni][r] * 0.125f - m);
            pv[ni][r] = e;
            s += e;
        }
        s += __shfl_xor(s, 1);
        s += __shfl_xor(s, 2);
        s += __shfl_xor(s, 4);
        s += __shfl_xor(s, 8);
        inv[r] = 1.f / s;
    }

    #pragma unroll
    for (int ni = 0; ni < 4; ++ni) {
        #pragma unroll
        for (int r = 0; r < 4; ++r) {
            int qrow = wave * 16 + g * 4 + r;
            int col = ni * 16 + lo;
            int byteoff = qrow * 128 + ((col * 2) ^ ((qrow & 7) << 4));
            *(unsigned short*)((char*)pS + byteoff) = f2b(pv[ni][r]);
        }
    }
    __syncthreads();  // barrier 2: pS + pTok ready

    f32x4 oacc[4] = {};
    #pragma unroll
    for (int s = 0; s < 2; ++s) {
        int arow2 = wave * 16 + lo;
        int abyte = arow2 * 128 + (((s * 32 + g * 8) * 2) ^ ((arow2 & 7) << 4));
        short8 pa = *(const short8*)((const char*)pS + abyte);
        #pragma unroll
        for (int nd = 0; nd < 4; ++nd) {
            int d = nd * 16 + lo;
            int bbyte = d * 128 + (((s * 32 + g * 8) * 2) ^ ((d & 7) << 4));
            short8 vb = *(const short8*)((const char*)vT + bbyte);
            oacc[nd] = __builtin_amdgcn_mfma_f32_16x16x32_bf16(pa, vb, oacc[nd], 0, 0, 0);
        }
    }

    {
        const int d = tid & 63, qq = tid >> 6;
        float po = 0.f;
        #pragma unroll
        for (int j16 = 0; j16 < 16; ++j16) {
            int j = qq * 16 + j16;
            int byteoff = d * 128 + ((j * 2) ^ ((d & 7) << 4));
            po = fmaf(pTok[j],
                      bf2f(*(const unsigned short*)((const char*)vT + byteoff)),
                      po);
        }
        oPart[qq][d] = po;
    }

    #pragma unroll
    for (int nd = 0; nd < 4; ++nd) {
        #pragma unroll
        for (int r = 0; r < 4; ++r) {
            int t = 1 + n * 64 + wave * 16 + g * 4 + r;
            aout[((size_t)b * Tc + t) * Dc + h * 64 + nd * 16 + lo] =
                __float2bfloat16(oacc[nd][r] * inv[r]);
        }
    }

    __syncthreads();  // barrier 3: oPart ready

    if (tid < 64) {
        float o0 = oPart[0][tid] + oPart[1][tid] + oPart[2][tid] + oPart[3][tid];
        float* pout = part + ((size_t)(b * Hc + h) * NW + n) * 66;
        pout[tid] = o0;
        if (tid == 0) { pout[64] = m_w; pout[65] = s_w; }
    }
}

// ---------------------------------------------------------------------------
// Token-0 reduce (r9 version, unchanged).
// ---------------------------------------------------------------------------
__global__ __launch_bounds__(64)
void k_tok0_reduce(const float* __restrict__ part, const bf16* __restrict__ qkv,
                   bf16* __restrict__ aout)
{
    const int h = blockIdx.x, b = blockIdx.y;
    const int lane = threadIdx.x;
    const float* basep = part + (size_t)(b * Hc + h) * NW * 66;
    const bf16* qrow = qkv + (size_t)b * Tc * 1536 + h * 64;

    float l0 = bf2f(*(const unsigned short*)(qrow + lane)) *
               bf2f(*(const unsigned short*)(qrow + 512 + lane));
    #pragma unroll
    for (int off = 1; off < 64; off <<= 1) l0 += __shfl_xor(l0, off);
    l0 *= 0.125f;

    float M = basep[lane * 66 + 64];
    #pragma unroll
    for (int off = 1; off < 64; off <<= 1) M = fmaxf(M, __shfl_xor(M, off));
    M = fmaxf(M, l0);

    float S = 0.f, o = 0.f;
    for (int c = 0; c < NW; ++c) {
        const float* pp = basep + c * 66;
        float w = __expf(pp[64] - M);
        S += pp[65] * w;
        o = fmaf(pp[lane], w, o);
    }
    float p0 = __expf(l0 - M);
    S += p0;
    o = fmaf(p0, bf2f(*(const unsigned short*)(qrow + 1024 + lane)), o);

    aout[(size_t)b * Tc * Dc + h * 64 + lane] = __float2bfloat16(o / S);
}

// ---------------------------------------------------------------------------
extern "C" void kernel_launch(void* const* d_in, const int* in_sizes, int n_in,
                              void* d_out, int out_size, void* d_ws, size_t ws_size,
                              hipStream_t stream)
{
    const float* x     = (const float*)d_in[0];
    const float* w_qkv = (const float*)d_in[1];
    const float* w_out = (const float*)d_in[2];
    float* out = (float*)d_out;

    // ws layout (bf16 elems): qkv [Mrows*1536] | xa [Mpad2*512] (xb & aout
    // share; rows >= Mrows stay zero from cvt_x pad) | wqT [1536*512] |
    // woT [512*512]. token-0 partials reuse wqT (dead after QKV GEMM).
    bf16* qkv = (bf16*)d_ws;
    bf16* xa  = qkv + (size_t)Mrows * 1536;
    bf16* wqT = xa  + (size_t)Mpad2 * 512;
    bf16* woT = wqT + (size_t)1536 * 512;
    float* part = (float*)wqT;

    // 1) conversions
    {
        int nblk = (int)(((size_t)Mpad2 * 512 / 8 + 255) / 256);
        k_cvt_x<<<nblk, 256, 0, stream>>>(x, xa);
    }
    k_cvt_wT<<<dim3(48, 16), 256, 0, stream>>>(w_qkv, wqT, 512, 1536);
    k_cvt_wT<<<dim3(16, 16), 256, 0, stream>>>(w_out, woT, 512, 512);

    // 2) qkv = x @ w_qkv  (256^2 8-phase fine-interleaved pipeline)
    k_gemm_8p<6><<<129 * 6, 512, 0, stream>>>(xa, wqT, qkv, Mrows);

    // 3) attention: MFMA windows with fused token-0 partials, then reduce
    k_attn_win<<<dim3(64, Hc, Bc), 256, 0, stream>>>(qkv, xa, part);
    k_tok0_reduce<<<dim3(Hc, Bc), dim3(64), 0, stream>>>(part, qkv, xa);

    // 4) out = attn_out @ w_out  (r6 dbuf — near memory floor)
    k_gemm_dbuf<float, 4><<<257 * 4, 256, 0, stream>>>(xa, woT, out, Mrows);
}